// Round 1
// baseline (65.861 us; speedup 1.0000x reference)
//
#include <hip/hip_runtime.h>
#include <math.h>

// Problem constants (fixed by the reference)
#define NPTS 8192
#define W_POS 0.1f
#define W_SCALE 0.1f
#define W_ROT 0.1f
#define W_COLOR 0.1f
#define WPB 4  // waves (rows) per block

__device__ __forceinline__ unsigned umin32(unsigned a, unsigned b) { return a < b ? a : b; }
__device__ __forceinline__ unsigned umax32(unsigned a, unsigned b) { return a > b ? a : b; }

// Pack positions into float4 {x, y, z, |x|^2}
__global__ void prep_kernel(const float* __restrict__ pos, float4* __restrict__ packed, int n) {
    int i = blockIdx.x * blockDim.x + threadIdx.x;
    if (i < n) {
        float x = pos[3 * i], y = pos[3 * i + 1], z = pos[3 * i + 2];
        float4 q;
        q.x = x; q.y = y; q.z = z;
        q.w = x * x + y * y + z * z;
        packed[i] = q;
    }
}

// One wave per row: top-7 smallest distances (incl. self), then per-row loss terms.
__global__ __launch_bounds__(256) void main_kernel(
    const float4* __restrict__ packed,
    const float* __restrict__ scales,
    const float* __restrict__ rots,
    const float* __restrict__ colors,
    float* __restrict__ partials, int n)
{
    const int lane = threadIdx.x & 63;
    const int wv = threadIdx.x >> 6;
    const int i = blockIdx.x * WPB + wv;
    if (i >= n) return;

    const float4 q = packed[i];
    const float sqi = q.w;

    // Sorted 7-smallest keys, ascending. Key = (d2 float bits & ~0x1FFF) | j.
    // d2 >= 0 so float bits are order-monotone; low 13 bits hold the index
    // (N=8192), which reproduces top_k's smaller-index tie-break.
    unsigned e0 = 0xFFFFFFFFu, e1 = 0xFFFFFFFFu, e2 = 0xFFFFFFFFu, e3 = 0xFFFFFFFFu,
             e4 = 0xFFFFFFFFu, e5 = 0xFFFFFFFFu, e6 = 0xFFFFFFFFu;

    for (int j = lane; j < n; j += 64) {
        float4 p = packed[j];
        float dot = fmaf(q.x, p.x, fmaf(q.y, p.y, q.z * p.z));
        float d2 = fmaf(-2.f, dot, sqi + p.w);
        d2 = fmaxf(d2, 0.f);
        unsigned key = (__float_as_uint(d2) & 0xFFFFE000u) | (unsigned)j;
        // Branchless sorted insert (drop current largest). Must read old e[k-1].
        e6 = umin32(e6, umax32(e5, key));
        e5 = umin32(e5, umax32(e4, key));
        e4 = umin32(e4, umax32(e3, key));
        e3 = umin32(e3, umax32(e2, key));
        e2 = umin32(e2, umax32(e1, key));
        e1 = umin32(e1, umax32(e0, key));
        e0 = umin32(e0, key);
    }

    // Merge 64 sorted lists: 7 rounds of {global-min of heads, owner pops}.
    // Keys are unique (index in low bits) so exactly one lane owns each min.
    unsigned out[7];
#pragma unroll
    for (int t = 0; t < 7; ++t) {
        unsigned v = e0;
#pragma unroll
        for (int off = 32; off; off >>= 1)
            v = umin32(v, (unsigned)__shfl_xor((int)v, off, 64));
        out[t] = v;  // uniform across lanes
        bool own = (e0 == v);
        e0 = own ? e1 : e0;
        e1 = own ? e2 : e1;
        e2 = own ? e3 : e2;
        e3 = own ? e4 : e3;
        e4 = own ? e5 : e4;
        e5 = own ? e6 : e5;
        e6 = own ? 0xFFFFFFFFu : e6;
    }

    // Position of self (d=0 -> key = i, always out[0] in practice; general anyway).
    int s = 6;
#pragma unroll
    for (int t = 6; t >= 0; --t)
        if ((out[t] & 8191u) == (unsigned)i) s = t;
    // Second-smallest OFF-diagonal distance (reference boosts the diagonal):
    // remove entry s from the sorted list, take element [1] of the remainder.
    unsigned sec_key = (s <= 1) ? out[2] : out[1];
    int nn2 = (int)(sec_key & 8191u);
    // Exact recompute of that distance (selection keys were truncated).
    float4 p2 = packed[nn2];
    float dot2 = fmaf(q.x, p2.x, fmaf(q.y, p2.y, q.z * p2.z));
    float d2e = fmaxf(fmaf(-2.f, dot2, sqi + p2.w), 0.f);
    float min_d = sqrtf(d2e);

    const float invn = 1.f / (float)n;
    float contrib = 0.f;
    if (lane < 15) {
        // 5 neighbors (list positions 1..5, matching nn_idx[:,1:]) x 3 channels
        int t = lane / 3;          // 0..4
        int ch = lane - t * 3;     // 0..2
        unsigned k = out[1];
        if (t == 1) k = out[2];
        if (t == 2) k = out[3];
        if (t == 3) k = out[4];
        if (t == 4) k = out[5];
        int nidx = (int)(k & 8191u);
        float a = colors[3 * i + ch];
        float b = colors[3 * nidx + ch];
        contrib = fabsf(a - b) * (W_COLOR * invn / 15.f);
    } else if (lane == 15) {
        contrib = expf(-min_d) * (W_POS * invn);
    } else if (lane == 16) {
        float s0 = scales[3 * i], s1 = scales[3 * i + 1], s2 = scales[3 * i + 2];
        float m = (s0 + s1 + s2) * (1.f / 3.f);
        float var = ((s0 - m) * (s0 - m) + (s1 - m) * (s1 - m) + (s2 - m) * (s2 - m)) * 0.5f;
        float al = fabsf(s0 - 1.f) + fabsf(s1 - 1.f) + fabsf(s2 - 1.f);
        contrib = W_SCALE * (al * (invn / 3.f) + var * invn);
    } else if (lane == 17) {
        float r0 = rots[4 * i], r1 = rots[4 * i + 1], r2 = rots[4 * i + 2], r3 = rots[4 * i + 3];
        float nm = sqrtf(r0 * r0 + r1 * r1 + r2 * r2 + r3 * r3);
        contrib = W_ROT * (nm - 1.f) * (nm - 1.f) * invn;
    } else if (lane == 18) {
        float c0 = colors[3 * i], c1 = colors[3 * i + 1], c2 = colors[3 * i + 2];
        contrib = W_COLOR * ((c0 - .5f) * (c0 - .5f) + (c1 - .5f) * (c1 - .5f) + (c2 - .5f) * (c2 - .5f)) * (invn / 3.f);
    }

#pragma unroll
    for (int off = 32; off; off >>= 1)
        contrib += __shfl_xor(contrib, off, 64);
    if (lane == 0) partials[i] = contrib;
}

// Deterministic final reduction (fixed tree, double accumulation).
__global__ void reduce_kernel(const float* __restrict__ partials, float* __restrict__ out, int n) {
    __shared__ double sm[256];
    double s = 0.0;
    for (int k = threadIdx.x; k < n; k += 256) s += (double)partials[k];
    sm[threadIdx.x] = s;
    __syncthreads();
    for (int step = 128; step; step >>= 1) {
        if ((int)threadIdx.x < step) sm[threadIdx.x] += sm[threadIdx.x + step];
        __syncthreads();
    }
    if (threadIdx.x == 0) out[0] = (float)sm[0];
}

extern "C" void kernel_launch(void* const* d_in, const int* in_sizes, int n_in,
                              void* d_out, int out_size, void* d_ws, size_t ws_size,
                              hipStream_t stream) {
    const float* pos = (const float*)d_in[0];
    const float* scales = (const float*)d_in[1];
    const float* rots = (const float*)d_in[2];
    const float* colors = (const float*)d_in[3];
    int n = in_sizes[0] / 3;  // 8192

    float4* packed = (float4*)d_ws;
    float* partials = (float*)((char*)d_ws + (size_t)n * sizeof(float4));

    prep_kernel<<<(n + 255) / 256, 256, 0, stream>>>(pos, packed, n);
    main_kernel<<<(n + WPB - 1) / WPB, 256, 0, stream>>>(packed, scales, rots, colors, partials, n);
    reduce_kernel<<<1, 256, 0, stream>>>(partials, (float*)d_out, n);
}

// Round 2
// 47.832 us; speedup vs baseline: 1.3769x; 1.3769x over previous
//
#include <hip/hip_runtime.h>
#include <math.h>

#define W_POS 0.1f
#define W_SCALE 0.1f
#define W_ROT 0.1f
#define W_COLOR 0.1f

__device__ __forceinline__ unsigned umed3(unsigned a, unsigned b, unsigned c) {
    unsigned d;
    asm("v_med3_u32 %0, %1, %2, %3" : "=v"(d) : "v"(a), "v"(b), "v"(c));
    return d;
}
__device__ __forceinline__ unsigned umin_(unsigned a, unsigned b) {
    unsigned d;
    asm("v_min_u32 %0, %1, %2" : "=v"(d) : "v"(a), "v"(b));
    return d;
}

// Insert key into ascending sorted 7-list e0..e6 (drops current max).
// e_k = min(e_k, max(e_{k-1}, key)) == med3(key, e_{k-1}, e_k) since e_{k-1} <= e_k.
#define INSERT7(keyv) do { unsigned _k = (keyv);  \
    e6 = umed3(_k, e5, e6);                       \
    e5 = umed3(_k, e4, e5);                       \
    e4 = umed3(_k, e3, e4);                       \
    e3 = umed3(_k, e2, e3);                       \
    e2 = umed3(_k, e1, e2);                       \
    e1 = umed3(_k, e0, e1);                       \
    e0 = umin_(e0, _k);  } while (0)

// Pack positions into float4 {x, y, z, |x|^2}
__global__ void prep_kernel(const float* __restrict__ pos, float4* __restrict__ packed, int n) {
    int i = blockIdx.x * blockDim.x + threadIdx.x;
    if (i < n) {
        float x = pos[3 * i], y = pos[3 * i + 1], z = pos[3 * i + 2];
        float4 q;
        q.x = x; q.y = y; q.z = z;
        q.w = x * x + y * y + z * z;
        packed[i] = q;
    }
}

// Lane owns row (g*64+lane); wave scans a wave-uniform candidate chunk via scalar loads.
// Each lane keeps the 7 smallest keys over its chunk; 4 waves/block merge via LDS;
// block writes one sorted 7-list per row per chunk s to `lists`.
__global__ __launch_bounds__(256) void pass_kernel(
    const float4* __restrict__ packed,
    unsigned* __restrict__ lists, int sbits, int n)
{
    const int lane = threadIdx.x & 63;
    const int wv = threadIdx.x >> 6;
    const int g = blockIdx.x;      // row group
    const int s = blockIdx.y;      // candidate super-chunk
    const int row = g * 64 + lane;
    const int per_wave = (n >> 2) >> sbits;   // candidates per wave

    const float4 q = packed[row];
    const float sqi = q.w;
    const float qx2 = -2.0f * q.x, qy2 = -2.0f * q.y, qz2 = -2.0f * q.z;

    unsigned e0 = 0xFFFFFFFFu, e1 = 0xFFFFFFFFu, e2 = 0xFFFFFFFFu, e3 = 0xFFFFFFFFu,
             e4 = 0xFFFFFFFFu, e5 = 0xFFFFFFFFu, e6 = 0xFFFFFFFFu;

    // wave-uniform base -> SGPR; candidate loads become s_load_dwordx4
    const int base = __builtin_amdgcn_readfirstlane((s * 4 + wv) * per_wave);
#pragma unroll 8
    for (int t = 0; t < per_wave; ++t) {
        float4 p = packed[base + t];
        float c0 = fmaf(qz2, p.z, sqi);
        float c1 = fmaf(qy2, p.y, c0);
        float c2 = fmaf(qx2, p.x, c1);
        float d2 = fmaxf(c2 + p.w, 0.0f);
        // truncate low 13 mantissa bits, pack candidate index -> order matches
        // top_k (value asc, then smaller index)
        unsigned key = (__float_as_uint(d2) & 0xFFFFE000u) | (unsigned)(base + t);
        INSERT7(key);
    }

    // intra-block merge: waves 1..3 publish, wave 0 inserts their 21 keys
    __shared__ unsigned sml[3][64][9];   // pad 9 to dodge bank conflicts
    if (wv > 0) {
        unsigned* p = sml[wv - 1][lane];
        p[0] = e0; p[1] = e1; p[2] = e2; p[3] = e3; p[4] = e4; p[5] = e5; p[6] = e6;
    }
    __syncthreads();
    if (wv == 0) {
#pragma unroll
        for (int w = 0; w < 3; ++w) {
            unsigned* p = sml[w][lane];
            INSERT7(p[0]); INSERT7(p[1]); INSERT7(p[2]); INSERT7(p[3]);
            INSERT7(p[4]); INSERT7(p[5]); INSERT7(p[6]);
        }
        unsigned* dst = lists + (((size_t)s * n + row) << 3);
        *(uint4*)dst = make_uint4(e0, e1, e2, e3);
        *(uint4*)(dst + 4) = make_uint4(e4, e5, e6, 0xFFFFFFFFu);
    }
}

// One thread per row: merge S sorted 7-lists, compute all per-row loss terms.
__global__ __launch_bounds__(256) void merge_kernel(
    const float4* __restrict__ packed,
    const unsigned* __restrict__ lists,
    const float* __restrict__ scales,
    const float* __restrict__ rots,
    const float* __restrict__ colors,
    double* __restrict__ bpart, int S, int n)
{
    const int r = blockIdx.x * 256 + threadIdx.x;

    unsigned e0 = 0xFFFFFFFFu, e1 = 0xFFFFFFFFu, e2 = 0xFFFFFFFFu, e3 = 0xFFFFFFFFu,
             e4 = 0xFFFFFFFFu, e5 = 0xFFFFFFFFu, e6 = 0xFFFFFFFFu;
    for (int s2 = 0; s2 < S; ++s2) {
        const uint4* p4 = (const uint4*)(lists + (((size_t)s2 * n + r) << 3));
        uint4 a = p4[0], b = p4[1];
        INSERT7(a.x); INSERT7(a.y); INSERT7(a.z); INSERT7(a.w);
        INSERT7(b.x); INSERT7(b.y); INSERT7(b.z);
    }

    // general self-exclusion (self may sit anywhere in the list, or be absent
    // if its d2 rounded negative)
    const unsigned M = 0x1FFFu;
    int spos = ((e0 & M) == (unsigned)r) ? 0 :
               ((e1 & M) == (unsigned)r) ? 1 :
               ((e2 & M) == (unsigned)r) ? 2 :
               ((e3 & M) == (unsigned)r) ? 3 :
               ((e4 & M) == (unsigned)r) ? 4 :
               ((e5 & M) == (unsigned)r) ? 5 :
               ((e6 & M) == (unsigned)r) ? 6 : 7;
    unsigned u0 = (spos == 0) ? e1 : e0;
    unsigned u1 = (spos <= 1) ? e2 : e1;
    unsigned u2 = (spos <= 2) ? e3 : e2;
    unsigned u3 = (spos <= 3) ? e4 : e3;
    unsigned u4 = (spos <= 4) ? e5 : e4;

    // exact recompute of 2nd-NN distance (selection keys were truncated)
    const float4 q = packed[r];
    const int i2 = (int)(u1 & M);
    const float4 p2 = packed[i2];
    float dot2 = fmaf(q.x, p2.x, fmaf(q.y, p2.y, q.z * p2.z));
    float d2e = fmaxf(q.w + p2.w - 2.0f * dot2, 0.0f);
    float min_d = sqrtf(d2e);

    // color smoothness over the 5 nearest (off-diag) neighbors
    float c0 = colors[3 * r], c1 = colors[3 * r + 1], c2 = colors[3 * r + 2];
    float cs = 0.0f;
    unsigned nb[5] = { u0, u1, u2, u3, u4 };
#pragma unroll
    for (int k = 0; k < 5; ++k) {
        int nidx = (int)(nb[k] & M);
        cs += fabsf(c0 - colors[3 * nidx]);
        cs += fabsf(c1 - colors[3 * nidx + 1]);
        cs += fabsf(c2 - colors[3 * nidx + 2]);
    }

    const float invn = 1.0f / (float)n;
    float s0 = scales[3 * r], s1 = scales[3 * r + 1], s2 = scales[3 * r + 2];
    float m = (s0 + s1 + s2) * (1.0f / 3.0f);
    float var = ((s0 - m) * (s0 - m) + (s1 - m) * (s1 - m) + (s2 - m) * (s2 - m)) * 0.5f;
    float al = fabsf(s0 - 1.0f) + fabsf(s1 - 1.0f) + fabsf(s2 - 1.0f);
    float r0 = rots[4 * r], r1 = rots[4 * r + 1], r2 = rots[4 * r + 2], r3 = rots[4 * r + 3];
    float nm = sqrtf(r0 * r0 + r1 * r1 + r2 * r2 + r3 * r3);

    float contrib =
        cs * (W_COLOR * invn / 15.0f) +
        expf(-min_d) * (W_POS * invn) +
        W_SCALE * (al * (invn / 3.0f) + var * invn) +
        W_ROT * (nm - 1.0f) * (nm - 1.0f) * invn +
        W_COLOR * ((c0 - .5f) * (c0 - .5f) + (c1 - .5f) * (c1 - .5f) + (c2 - .5f) * (c2 - .5f)) * (invn / 3.0f);

    __shared__ double sm[256];
    sm[threadIdx.x] = (double)contrib;
    __syncthreads();
    for (int step = 128; step; step >>= 1) {
        if ((int)threadIdx.x < step) sm[threadIdx.x] += sm[threadIdx.x + step];
        __syncthreads();
    }
    if (threadIdx.x == 0) bpart[blockIdx.x] = sm[0];
}

__global__ void final_kernel(const double* __restrict__ bpart, float* __restrict__ out, int nb) {
    if (threadIdx.x == 0) {
        double s = 0.0;
        for (int i = 0; i < nb; ++i) s += bpart[i];
        out[0] = (float)s;
    }
}

extern "C" void kernel_launch(void* const* d_in, const int* in_sizes, int n_in,
                              void* d_out, int out_size, void* d_ws, size_t ws_size,
                              hipStream_t stream) {
    const float* pos = (const float*)d_in[0];
    const float* scales = (const float*)d_in[1];
    const float* rots = (const float*)d_in[2];
    const float* colors = (const float*)d_in[3];
    int n = in_sizes[0] / 3;  // 8192

    float4* packed = (float4*)d_ws;
    size_t off = (size_t)n * sizeof(float4);

    // pick the largest candidate-split S = 2^sbits that fits the workspace
    int sbits = 4;
    while (sbits > 0) {
        size_t need = off + (((size_t)1 << sbits) * n) * 32 + 4096;
        if (need <= ws_size) break;
        --sbits;
    }
    int S = 1 << sbits;
    unsigned* lists = (unsigned*)((char*)d_ws + off);
    double* bpart = (double*)((char*)d_ws + off + ((size_t)S * n) * 32);

    int nrowg = n / 64;
    int nmb = n / 256;

    prep_kernel<<<(n + 255) / 256, 256, 0, stream>>>(pos, packed, n);
    pass_kernel<<<dim3(nrowg, S), 256, 0, stream>>>(packed, lists, sbits, n);
    merge_kernel<<<nmb, 256, 0, stream>>>(packed, lists, scales, rots, colors, bpart, S, n);
    final_kernel<<<1, 64, 0, stream>>>(bpart, (float*)d_out, nmb);
}